// Round 4
// baseline (288.314 us; speedup 1.0000x reference)
//
#include <hip/hip_runtime.h>
#include <cstdint>
#include <cstddef>

#define N_TOK 32768
#define DIM   1024
#define NE    64
#define RPB   64            // rows per block
#define CH    64            // k per staged chunk
#define NCH   (DIM / CH)    // 16

// global -> LDS direct DMA, 16B per lane; LDS dest = wave-uniform base + lane*16
__device__ __forceinline__ void gload16(const float* g, float* l) {
  __builtin_amdgcn_global_load_lds(
      (const __attribute__((address_space(1))) uint32_t*)g,
      (__attribute__((address_space(3))) uint32_t*)l, 16, 0, 0);
}

__global__ __launch_bounds__(512, 4) void router_kernel(
    const float* __restrict__ x, const float* __restrict__ W,
    const float* __restrict__ bias, float* __restrict__ probs,
    float* __restrict__ idxo) {
  // 64 KB LDS:
  //  [0,32768):    xT [buf 2][kk 64][col 64]  x-transpose; col = row ^ ((kk>>3)<<3)
  //  [32768,65536): wB [buf 2][kk 64][e 64]   linear
  //  reduction phase reuses all 64 KB as 4 tiles of [64][64] fp32
  __shared__ __align__(1024) float smem[16384];
  float* xT = smem;          // [2][64][64]
  float* wB = smem + 8192;   // [2][64][64]

  const int tid  = threadIdx.x;
  const int lane = tid & 63;
  const int w    = __builtin_amdgcn_readfirstlane(tid >> 6);  // 0..7 (k-slice)
  const int ri   = lane >> 3;      // row-block 0..7 (8 rows each)
  const int ei   = lane & 7;       // e-block 0..7 (8 experts each)
  const int r0   = blockIdx.x * RPB;

  // x staging mapping: thread -> (srow, sq); stages quads sq and sq+8 of its row
  const int srow = tid >> 3;       // 0..63
  const int sq   = tid & 7;        // 0..7
  const float* xrow = x + (size_t)(r0 + srow) * DIM + sq * 4;

  float acc[64];
#pragma unroll
  for (int i = 0; i < 64; ++i) acc[i] = 0.0f;

  // swizzled column indices (constant per thread)
  const int rp0 = srow ^ ((sq >> 1) << 3);          // for quad sq   (kk>>3 = sq>>1)
  const int rp1 = srow ^ ((((sq + 8) >> 1)) << 3);  // for quad sq+8

  // ---- prologue: stage chunk 0 into buf 0 ----
  float4 xg0 = *(const float4*)(xrow);
  float4 xg1 = *(const float4*)(xrow + 32);
#pragma unroll
  for (int jj = 0; jj < 2; ++jj) {
    const int j = w * 2 + jj;                       // 1 KB DMA slice j: rows j*4..+4
    gload16(W + (size_t)(j * 4) * NE + lane * 4, wB + j * 256);
  }
  {
    float* xb = xT;
    const int q1 = sq + 8;
    xb[(sq*4+0)*64 + rp0] = xg0.x;  xb[(sq*4+1)*64 + rp0] = xg0.y;
    xb[(sq*4+2)*64 + rp0] = xg0.z;  xb[(sq*4+3)*64 + rp0] = xg0.w;
    xb[(q1*4+0)*64 + rp1] = xg1.x;  xb[(q1*4+1)*64 + rp1] = xg1.y;
    xb[(q1*4+2)*64 + rp1] = xg1.z;  xb[(q1*4+3)*64 + rp1] = xg1.w;
  }

  for (int cc = 0; cc < NCH; ++cc) {
    __syncthreads();                 // buf[cc&1] ready (x ds_writes + W DMA drained)
    const int buf = cc & 1;
    const int nb  = buf ^ 1;
    const bool pf = (cc + 1 < NCH);

    if (pf) {                        // issue next chunk's global traffic early
      const int k0n = (cc + 1) * CH;
      xg0 = *(const float4*)(xrow + k0n);
      xg1 = *(const float4*)(xrow + k0n + 32);
#pragma unroll
      for (int jj = 0; jj < 2; ++jj) {
        const int j = w * 2 + jj;
        gload16(W + (size_t)(k0n + j * 4) * NE + lane * 4,
                wB + nb * 4096 + j * 256);
      }
    }

    // ---- compute: wave w handles kk = w*8 .. w*8+8 of this chunk ----
    // read swizzle: for kk in [w*8, w*8+8), kk>>3 == w, so row-block index is ri^w
    const float* xbr = xT + buf * 4096 + ((ri ^ w) * 8);
    const float* wbr = wB + buf * 4096 + ei * 8;
#pragma unroll
    for (int i = 0; i < 8; ++i) {
      const int kk = w * 8 + i;
      const float4 xa = *(const float4*)(xbr + kk * 64);
      const float4 xc = *(const float4*)(xbr + kk * 64 + 4);
      const float4 wa = *(const float4*)(wbr + kk * 64);
      const float4 wc = *(const float4*)(wbr + kk * 64 + 4);
#define ROUTER_FMA_ROW(J, XS)                                   \
      acc[(J)*8+0] = fmaf(XS, wa.x, acc[(J)*8+0]);              \
      acc[(J)*8+1] = fmaf(XS, wa.y, acc[(J)*8+1]);              \
      acc[(J)*8+2] = fmaf(XS, wa.z, acc[(J)*8+2]);              \
      acc[(J)*8+3] = fmaf(XS, wa.w, acc[(J)*8+3]);              \
      acc[(J)*8+4] = fmaf(XS, wc.x, acc[(J)*8+4]);              \
      acc[(J)*8+5] = fmaf(XS, wc.y, acc[(J)*8+5]);              \
      acc[(J)*8+6] = fmaf(XS, wc.z, acc[(J)*8+6]);              \
      acc[(J)*8+7] = fmaf(XS, wc.w, acc[(J)*8+7]);
      ROUTER_FMA_ROW(0, xa.x)
      ROUTER_FMA_ROW(1, xa.y)
      ROUTER_FMA_ROW(2, xa.z)
      ROUTER_FMA_ROW(3, xa.w)
      ROUTER_FMA_ROW(4, xc.x)
      ROUTER_FMA_ROW(5, xc.y)
      ROUTER_FMA_ROW(6, xc.z)
      ROUTER_FMA_ROW(7, xc.w)
#undef ROUTER_FMA_ROW
    }

    if (pf) {                        // transpose-write next x chunk (vmcnt waited here)
      float* xb = xT + nb * 4096;
      const int q1 = sq + 8;
      xb[(sq*4+0)*64 + rp0] = xg0.x;  xb[(sq*4+1)*64 + rp0] = xg0.y;
      xb[(sq*4+2)*64 + rp0] = xg0.z;  xb[(sq*4+3)*64 + rp0] = xg0.w;
      xb[(q1*4+0)*64 + rp1] = xg1.x;  xb[(q1*4+1)*64 + rp1] = xg1.y;
      xb[(q1*4+2)*64 + rp1] = xg1.z;  xb[(q1*4+3)*64 + rp1] = xg1.w;
    }
  }

  // ---- cross-wave k-reduction: pairwise tree over the 8 k-slices ----
  auto write_tile = [&](float* T) {
#pragma unroll
    for (int j = 0; j < 8; ++j) {
      *(float4*)(T + (ri*8+j)*64 + ei*8) =
          make_float4(acc[j*8+0], acc[j*8+1], acc[j*8+2], acc[j*8+3]);
      *(float4*)(T + (ri*8+j)*64 + ei*8 + 4) =
          make_float4(acc[j*8+4], acc[j*8+5], acc[j*8+6], acc[j*8+7]);
    }
  };
  auto add_tile = [&](const float* T) {
#pragma unroll
    for (int j = 0; j < 8; ++j) {
      const float4 a = *(const float4*)(T + (ri*8+j)*64 + ei*8);
      const float4 b = *(const float4*)(T + (ri*8+j)*64 + ei*8 + 4);
      acc[j*8+0] += a.x; acc[j*8+1] += a.y; acc[j*8+2] += a.z; acc[j*8+3] += a.w;
      acc[j*8+4] += b.x; acc[j*8+5] += b.y; acc[j*8+6] += b.z; acc[j*8+7] += b.w;
    }
  };

  __syncthreads();
  if (w >= 4) write_tile(smem + (w - 4) * 4096);
  __syncthreads();
  if (w < 4) add_tile(smem + w * 4096);
  __syncthreads();
  if (w == 2 || w == 3) write_tile(smem + w * 4096);
  __syncthreads();
  if (w < 2) add_tile(smem + (w + 2) * 4096);
  __syncthreads();
  if (w == 1) write_tile(smem + 4096);
  __syncthreads();

  if (w == 0) {
    add_tile(smem + 4096);           // full k-sum now in wave 0's acc

    // bias
    const float4 b0 = *(const float4*)(bias + ei * 8);
    const float4 b1 = *(const float4*)(bias + ei * 8 + 4);
#pragma unroll
    for (int j = 0; j < 8; ++j) {
      acc[j*8+0] += b0.x; acc[j*8+1] += b0.y; acc[j*8+2] += b0.z; acc[j*8+3] += b0.w;
      acc[j*8+4] += b1.x; acc[j*8+5] += b1.y; acc[j*8+6] += b1.z; acc[j*8+7] += b1.w;
    }

    // per row: local top2 over this lane's 8 experts, then butterfly over ei
#pragma unroll
    for (int j = 0; j < 8; ++j) {
      float v1, v2, j1, j2;
      {
        const float a0 = acc[j*8+0], a1 = acc[j*8+1];
        if (a1 > a0) { v1 = a1; j1 = (float)(ei*8+1); v2 = a0; j2 = (float)(ei*8+0); }
        else         { v1 = a0; j1 = (float)(ei*8+0); v2 = a1; j2 = (float)(ei*8+1); }
#pragma unroll
        for (int e = 2; e < 8; ++e) {
          const float a = acc[j*8+e]; const float jf = (float)(ei*8+e);
          if (a > v1)      { v2 = v1; j2 = j1; v1 = a; j1 = jf; }
          else if (a > v2) { v2 = a; j2 = jf; }
        }
      }
#pragma unroll
      for (int m = 1; m <= 4; m <<= 1) {    // merge across the 8 ei lanes
        const float u1  = __shfl_xor(v1, m, 64);
        const float uj1 = __shfl_xor(j1, m, 64);
        const float u2  = __shfl_xor(v2, m, 64);
        const float uj2 = __shfl_xor(j2, m, 64);
        const bool uwin = (u1 > v1) || (u1 == v1 && uj1 < j1);
        const float t1 = uwin ? u1 : v1,  tj1 = uwin ? uj1 : j1;
        const float l1 = uwin ? v1 : u1,  lj1 = uwin ? j1 : uj1;
        const float c2 = uwin ? u2 : v2,  cj2 = uwin ? uj2 : j2;
        const bool sw = (c2 > l1) || (c2 == l1 && cj2 < lj1);
        v1 = t1; j1 = tj1;
        v2 = sw ? c2 : l1; j2 = sw ? cj2 : lj1;
      }
      const float e2 = __expf(v2 - v1);
      const float p1 = 1.0f / (1.0f + e2);
      const float p2 = e2 * p1;
      const int row = r0 + ri * 8 + j;
      const int ij1 = (int)j1, ij2 = (int)j2;
      float* op = probs + (size_t)row * NE + ei * 8;
      float4 o0, o1;
      const int e0 = ei * 8;
      o0.x = (e0+0 == ij1) ? p1 : (e0+0 == ij2) ? p2 : 0.0f;
      o0.y = (e0+1 == ij1) ? p1 : (e0+1 == ij2) ? p2 : 0.0f;
      o0.z = (e0+2 == ij1) ? p1 : (e0+2 == ij2) ? p2 : 0.0f;
      o0.w = (e0+3 == ij1) ? p1 : (e0+3 == ij2) ? p2 : 0.0f;
      o1.x = (e0+4 == ij1) ? p1 : (e0+4 == ij2) ? p2 : 0.0f;
      o1.y = (e0+5 == ij1) ? p1 : (e0+5 == ij2) ? p2 : 0.0f;
      o1.z = (e0+6 == ij1) ? p1 : (e0+6 == ij2) ? p2 : 0.0f;
      o1.w = (e0+7 == ij1) ? p1 : (e0+7 == ij2) ? p2 : 0.0f;
      *(float4*)(op) = o0;
      *(float4*)(op + 4) = o1;
      if (ei == 0) {
        float2 oi; oi.x = j1; oi.y = j2;
        *(float2*)(idxo + (size_t)row * 2) = oi;
      }
    }
  }
}

extern "C" void kernel_launch(void* const* d_in, const int* in_sizes, int n_in,
                              void* d_out, int out_size, void* d_ws, size_t ws_size,
                              hipStream_t stream) {
  (void)in_sizes; (void)n_in; (void)out_size; (void)d_ws; (void)ws_size;
  const float* x = (const float*)d_in[0];
  const float* W = (const float*)d_in[1];
  const float* b = (const float*)d_in[2];
  float* out  = (float*)d_out;
  float* idxo = out + (size_t)N_TOK * NE;   // indices chunk follows probs chunk

  dim3 grid(N_TOK / RPB);   // 512 blocks
  dim3 block(512);
  hipLaunchKernelGGL(router_kernel, grid, block, 0, stream, x, W, b, out, idxo);
}

// Round 5
// 235.435 us; speedup vs baseline: 1.2246x; 1.2246x over previous
//
#include <hip/hip_runtime.h>
#include <cstdint>
#include <cstddef>

#define N_TOK 32768
#define DIM   1024
#define NE    64
#define RPB   64            // rows per block
#define CH    64            // k per staged chunk
#define NCH   (DIM / CH)    // 16

// global -> LDS direct DMA, 16B per lane; LDS dest = wave-uniform base + lane*16
__device__ __forceinline__ void gload16(const float* g, float* l) {
  __builtin_amdgcn_global_load_lds(
      (const __attribute__((address_space(1))) uint32_t*)g,
      (__attribute__((address_space(3))) uint32_t*)l, 16, 0, 0);
}

// NOTE: second arg = 2 (not 4): empirically this toolchain treats it as a
// min-resident-blocks/CU bound; 4 imposed a 64-VGPR cap and spilled acc[]
// to scratch (WRITE_SIZE 8.4->169 MB, VGPR_Count=64). 2 -> 128-VGPR cap,
// still 2 blocks/CU (LDS 64KB is the binding limit anyway).
__global__ __launch_bounds__(512, 2) void router_kernel(
    const float* __restrict__ x, const float* __restrict__ W,
    const float* __restrict__ bias, float* __restrict__ probs,
    float* __restrict__ idxo) {
  // 64 KB LDS:
  //  [0,32768):    xT [buf 2][kk 64][col 64]  x-transpose; col = row ^ ((kk>>3)<<3)
  //  [32768,65536): wB [buf 2][kk 64][e 64]   linear
  //  reduction phase reuses all 64 KB as 4 tiles of [64][64] fp32
  __shared__ __align__(1024) float smem[16384];
  float* xT = smem;          // [2][64][64]
  float* wB = smem + 8192;   // [2][64][64]

  const int tid  = threadIdx.x;
  const int lane = tid & 63;
  const int w    = __builtin_amdgcn_readfirstlane(tid >> 6);  // 0..7 (k-slice)
  const int ri   = lane >> 3;      // row-block 0..7 (8 rows each)
  const int ei   = lane & 7;       // e-block 0..7 (8 experts each)
  const int r0   = blockIdx.x * RPB;

  // x staging mapping: thread -> (srow, sq); stages quads sq and sq+8 of its row
  const int srow = tid >> 3;       // 0..63
  const int sq   = tid & 7;        // 0..7
  const float* xrow = x + (size_t)(r0 + srow) * DIM + sq * 4;

  float acc[64];
#pragma unroll
  for (int i = 0; i < 64; ++i) acc[i] = 0.0f;

  // swizzled column indices (constant per thread)
  const int rp0 = srow ^ ((sq >> 1) << 3);          // for quad sq   (kk>>3 = sq>>1)
  const int rp1 = srow ^ ((((sq + 8) >> 1)) << 3);  // for quad sq+8

  // ---- prologue: stage chunk 0 into buf 0 ----
  float4 xg0 = *(const float4*)(xrow);
  float4 xg1 = *(const float4*)(xrow + 32);
#pragma unroll
  for (int jj = 0; jj < 2; ++jj) {
    const int j = w * 2 + jj;                       // 1 KB DMA slice j: rows j*4..+4
    gload16(W + (size_t)(j * 4) * NE + lane * 4, wB + j * 256);
  }
  {
    float* xb = xT;
    const int q1 = sq + 8;
    xb[(sq*4+0)*64 + rp0] = xg0.x;  xb[(sq*4+1)*64 + rp0] = xg0.y;
    xb[(sq*4+2)*64 + rp0] = xg0.z;  xb[(sq*4+3)*64 + rp0] = xg0.w;
    xb[(q1*4+0)*64 + rp1] = xg1.x;  xb[(q1*4+1)*64 + rp1] = xg1.y;
    xb[(q1*4+2)*64 + rp1] = xg1.z;  xb[(q1*4+3)*64 + rp1] = xg1.w;
  }

  for (int cc = 0; cc < NCH; ++cc) {
    __syncthreads();                 // buf[cc&1] ready (x ds_writes + W DMA drained)
    const int buf = cc & 1;
    const int nb  = buf ^ 1;
    const bool pf = (cc + 1 < NCH);

    if (pf) {                        // issue next chunk's global traffic early
      const int k0n = (cc + 1) * CH;
      xg0 = *(const float4*)(xrow + k0n);
      xg1 = *(const float4*)(xrow + k0n + 32);
#pragma unroll
      for (int jj = 0; jj < 2; ++jj) {
        const int j = w * 2 + jj;
        gload16(W + (size_t)(k0n + j * 4) * NE + lane * 4,
                wB + nb * 4096 + j * 256);
      }
    }

    // ---- compute: wave w handles kk = w*8 .. w*8+8 of this chunk ----
    // read swizzle: for kk in [w*8, w*8+8), kk>>3 == w, so row-block index is ri^w
    // base pointers absorb w*512 so the 32 ds_reads use immediate offsets only
    const float* xkb = xT + buf * 4096 + w * 512 + ((ri ^ w) * 8);
    const float* wkb = wB + buf * 4096 + w * 512 + ei * 8;
#pragma unroll
    for (int i = 0; i < 8; ++i) {
      const float4 xa = *(const float4*)(xkb + i * 64);
      const float4 xc = *(const float4*)(xkb + i * 64 + 4);
      const float4 wa = *(const float4*)(wkb + i * 64);
      const float4 wc = *(const float4*)(wkb + i * 64 + 4);
#define ROUTER_FMA_ROW(J, XS)                                   \
      acc[(J)*8+0] = fmaf(XS, wa.x, acc[(J)*8+0]);              \
      acc[(J)*8+1] = fmaf(XS, wa.y, acc[(J)*8+1]);              \
      acc[(J)*8+2] = fmaf(XS, wa.z, acc[(J)*8+2]);              \
      acc[(J)*8+3] = fmaf(XS, wa.w, acc[(J)*8+3]);              \
      acc[(J)*8+4] = fmaf(XS, wc.x, acc[(J)*8+4]);              \
      acc[(J)*8+5] = fmaf(XS, wc.y, acc[(J)*8+5]);              \
      acc[(J)*8+6] = fmaf(XS, wc.z, acc[(J)*8+6]);              \
      acc[(J)*8+7] = fmaf(XS, wc.w, acc[(J)*8+7]);
      ROUTER_FMA_ROW(0, xa.x)
      ROUTER_FMA_ROW(1, xa.y)
      ROUTER_FMA_ROW(2, xa.z)
      ROUTER_FMA_ROW(3, xa.w)
      ROUTER_FMA_ROW(4, xc.x)
      ROUTER_FMA_ROW(5, xc.y)
      ROUTER_FMA_ROW(6, xc.z)
      ROUTER_FMA_ROW(7, xc.w)
#undef ROUTER_FMA_ROW
    }

    if (pf) {                        // transpose-write next x chunk (vmcnt waited here)
      float* xb = xT + nb * 4096;
      const int q1 = sq + 8;
      xb[(sq*4+0)*64 + rp0] = xg0.x;  xb[(sq*4+1)*64 + rp0] = xg0.y;
      xb[(sq*4+2)*64 + rp0] = xg0.z;  xb[(sq*4+3)*64 + rp0] = xg0.w;
      xb[(q1*4+0)*64 + rp1] = xg1.x;  xb[(q1*4+1)*64 + rp1] = xg1.y;
      xb[(q1*4+2)*64 + rp1] = xg1.z;  xb[(q1*4+3)*64 + rp1] = xg1.w;
    }
  }

  // ---- cross-wave k-reduction: pairwise tree over the 8 k-slices ----
  auto write_tile = [&](float* T) {
#pragma unroll
    for (int j = 0; j < 8; ++j) {
      *(float4*)(T + (ri*8+j)*64 + ei*8) =
          make_float4(acc[j*8+0], acc[j*8+1], acc[j*8+2], acc[j*8+3]);
      *(float4*)(T + (ri*8+j)*64 + ei*8 + 4) =
          make_float4(acc[j*8+4], acc[j*8+5], acc[j*8+6], acc[j*8+7]);
    }
  };
  auto add_tile = [&](const float* T) {
#pragma unroll
    for (int j = 0; j < 8; ++j) {
      const float4 a = *(const float4*)(T + (ri*8+j)*64 + ei*8);
      const float4 b = *(const float4*)(T + (ri*8+j)*64 + ei*8 + 4);
      acc[j*8+0] += a.x; acc[j*8+1] += a.y; acc[j*8+2] += a.z; acc[j*8+3] += a.w;
      acc[j*8+4] += b.x; acc[j*8+5] += b.y; acc[j*8+6] += b.z; acc[j*8+7] += b.w;
    }
  };

  __syncthreads();
  if (w >= 4) write_tile(smem + (w - 4) * 4096);
  __syncthreads();
  if (w < 4) add_tile(smem + w * 4096);
  __syncthreads();
  if (w == 2 || w == 3) write_tile(smem + w * 4096);
  __syncthreads();
  if (w < 2) add_tile(smem + (w + 2) * 4096);
  __syncthreads();
  if (w == 1) write_tile(smem + 4096);
  __syncthreads();

  if (w == 0) {
    add_tile(smem + 4096);           // full k-sum now in wave 0's acc

    // bias
    const float4 b0 = *(const float4*)(bias + ei * 8);
    const float4 b1 = *(const float4*)(bias + ei * 8 + 4);
#pragma unroll
    for (int j = 0; j < 8; ++j) {
      acc[j*8+0] += b0.x; acc[j*8+1] += b0.y; acc[j*8+2] += b0.z; acc[j*8+3] += b0.w;
      acc[j*8+4] += b1.x; acc[j*8+5] += b1.y; acc[j*8+6] += b1.z; acc[j*8+7] += b1.w;
    }

    // per row: local top2 over this lane's 8 experts, then butterfly over ei
#pragma unroll
    for (int j = 0; j < 8; ++j) {
      float v1, v2, j1, j2;
      {
        const float a0 = acc[j*8+0], a1 = acc[j*8+1];
        if (a1 > a0) { v1 = a1; j1 = (float)(ei*8+1); v2 = a0; j2 = (float)(ei*8+0); }
        else         { v1 = a0; j1 = (float)(ei*8+0); v2 = a1; j2 = (float)(ei*8+1); }
#pragma unroll
        for (int e = 2; e < 8; ++e) {
          const float a = acc[j*8+e]; const float jf = (float)(ei*8+e);
          if (a > v1)      { v2 = v1; j2 = j1; v1 = a; j1 = jf; }
          else if (a > v2) { v2 = a; j2 = jf; }
        }
      }
#pragma unroll
      for (int m = 1; m <= 4; m <<= 1) {    // merge across the 8 ei lanes
        const float u1  = __shfl_xor(v1, m, 64);
        const float uj1 = __shfl_xor(j1, m, 64);
        const float u2  = __shfl_xor(v2, m, 64);
        const float uj2 = __shfl_xor(j2, m, 64);
        const bool uwin = (u1 > v1) || (u1 == v1 && uj1 < j1);
        const float t1 = uwin ? u1 : v1,  tj1 = uwin ? uj1 : j1;
        const float l1 = uwin ? v1 : u1,  lj1 = uwin ? j1 : uj1;
        const float c2 = uwin ? u2 : v2,  cj2 = uwin ? uj2 : j2;
        const bool sw = (c2 > l1) || (c2 == l1 && cj2 < lj1);
        v1 = t1; j1 = tj1;
        v2 = sw ? c2 : l1; j2 = sw ? cj2 : lj1;
      }
      const float e2 = __expf(v2 - v1);
      const float p1 = 1.0f / (1.0f + e2);
      const float p2 = e2 * p1;
      const int row = r0 + ri * 8 + j;
      const int ij1 = (int)j1, ij2 = (int)j2;
      float* op = probs + (size_t)row * NE + ei * 8;
      float4 o0, o1;
      const int e0 = ei * 8;
      o0.x = (e0+0 == ij1) ? p1 : (e0+0 == ij2) ? p2 : 0.0f;
      o0.y = (e0+1 == ij1) ? p1 : (e0+1 == ij2) ? p2 : 0.0f;
      o0.z = (e0+2 == ij1) ? p1 : (e0+2 == ij2) ? p2 : 0.0f;
      o0.w = (e0+3 == ij1) ? p1 : (e0+3 == ij2) ? p2 : 0.0f;
      o1.x = (e0+4 == ij1) ? p1 : (e0+4 == ij2) ? p2 : 0.0f;
      o1.y = (e0+5 == ij1) ? p1 : (e0+5 == ij2) ? p2 : 0.0f;
      o1.z = (e0+6 == ij1) ? p1 : (e0+6 == ij2) ? p2 : 0.0f;
      o1.w = (e0+7 == ij1) ? p1 : (e0+7 == ij2) ? p2 : 0.0f;
      *(float4*)(op) = o0;
      *(float4*)(op + 4) = o1;
      if (ei == 0) {
        float2 oi; oi.x = j1; oi.y = j2;
        *(float2*)(idxo + (size_t)row * 2) = oi;
      }
    }
  }
}

extern "C" void kernel_launch(void* const* d_in, const int* in_sizes, int n_in,
                              void* d_out, int out_size, void* d_ws, size_t ws_size,
                              hipStream_t stream) {
  (void)in_sizes; (void)n_in; (void)out_size; (void)d_ws; (void)ws_size;
  const float* x = (const float*)d_in[0];
  const float* W = (const float*)d_in[1];
  const float* b = (const float*)d_in[2];
  float* out  = (float*)d_out;
  float* idxo = out + (size_t)N_TOK * NE;   // indices chunk follows probs chunk

  dim3 grid(N_TOK / RPB);   // 512 blocks
  dim3 block(512);
  hipLaunchKernelGGL(router_kernel, grid, block, 0, stream, x, W, b, out, idxo);
}